// Round 5
// baseline (645.200 us; speedup 1.0000x reference)
//
#include <hip/hip_runtime.h>
#include <hip/hip_bf16.h>

typedef __bf16    bf16x8_t __attribute__((ext_vector_type(8)));
typedef float     f32x4_t  __attribute__((ext_vector_type(4)));
typedef short     s16x8_t  __attribute__((ext_vector_type(8)));
typedef unsigned  u32x4_t  __attribute__((ext_vector_type(4)));

#define S_LEN    2048
#define HDIM     64
#define BQ       16
#define NTHREADS 512
#define PSTR     2056   // P row stride (bf16 elems), 16B-aligned rows
#define QSTR     72
#define BMSTR    264    // bitmask row stride (bytes)

__device__ __forceinline__ short f2bf(float f) {
    return __builtin_bit_cast(short, (__bf16)f);   // native RNE cvt
}
__device__ __forceinline__ float bf2f(short s) {
    return __builtin_bit_cast(float, ((unsigned)(unsigned short)s) << 16);
}

// Detect on-device mask dtype from byte pattern (first 16 KB). See r1 notes.
__global__ void detect_mask(const unsigned char* __restrict__ M, int* __restrict__ flags) {
    __shared__ int cnt[4];
    if (threadIdx.x < 4) cnt[threadIdx.x] = 0;
    __syncthreads();
    int local[4] = {0, 0, 0, 0};
    for (int i = threadIdx.x; i < 16384; i += 256)
        if (M[i]) local[i & 3]++;
    #pragma unroll
    for (int c = 0; c < 4; ++c)
        if (local[c]) atomicAdd(&cnt[c], local[c]);
    __syncthreads();
    if (threadIdx.x == 0) {
        int stride;
        if (cnt[1] == 0 && cnt[2] == 0 && cnt[3] == 0)      stride = 4;  // int32
        else if (cnt[0] == 0 && cnt[1] == 0)                stride = 4;  // float32
        else                                                stride = 1;  // bool/int8
        flags[0] = stride;
    }
}

__global__ __launch_bounds__(NTHREADS, 4)
void sdpa_fused(const float* __restrict__ Q, const float* __restrict__ K,
                const float* __restrict__ V, const unsigned char* __restrict__ M,
                const int* __restrict__ MF, float* __restrict__ OUT)
{
    __shared__ short Plds[BQ * PSTR];            // 65792 B masked exp(score) bf16
    __shared__ short Qlds[BQ * QSTR];            // 2304 B
    __shared__ unsigned char Bm[BQ * BMSTR];     // 4224 B mask bitmask
    __shared__ float Pvp[4][BQ][17];             // 4352 B PV k-split partials
    __shared__ float rowsum[BQ];
    __shared__ float rinv[BQ];

    const int tid  = threadIdx.x;
    const int wave = tid >> 6;
    const int lane = tid & 63;
    const int col  = lane & 15;
    const int kg   = lane >> 4;
    const int mstride = MF[0];

    // 4096 blocks = 8 xcd * 512 slots; all 128 q-tiles of one b on one XCD
    const int id   = blockIdx.x;
    const int slot = id >> 3;
    const int b    = ((slot >> 7) << 3) | (id & 7);
    const int q0   = (slot & 127) * BQ;

    float* ctx_out  = OUT;
    float* attn_out = OUT + (size_t)32 * S_LEN * HDIM;

    // ---- Phase 0: Q -> LDS (bf16); mask tile -> 1-bit/elem LDS bitmask
    {
        const int r  = tid >> 5;
        const int h2 = (tid & 31) * 2;
        const float2 qv = *(const float2*)(Q + ((size_t)b * S_LEN + q0 + r) * HDIM + h2);
        Qlds[r * QSTR + h2]     = f2bf(qv.x);
        Qlds[r * QSTR + h2 + 1] = f2bf(qv.y);
        if (tid < BQ) rowsum[tid] = 0.f;
    }
    {
        const int row = tid >> 5;          // 0..15
        const int seg = (tid & 31) * 64;   // element offset within row
        unsigned nib[16];
        if (mstride == 1) {
            const unsigned char* mp = M + (size_t)b * S_LEN * S_LEN
                                        + (size_t)(q0 + row) * S_LEN + seg;
            const u32x4_t m0 = __builtin_nontemporal_load((const u32x4_t*)(mp));
            const u32x4_t m1 = __builtin_nontemporal_load((const u32x4_t*)(mp + 16));
            const u32x4_t m2 = __builtin_nontemporal_load((const u32x4_t*)(mp + 32));
            const u32x4_t m3 = __builtin_nontemporal_load((const u32x4_t*)(mp + 48));
            const unsigned w[16] = {m0[0],m0[1],m0[2],m0[3], m1[0],m1[1],m1[2],m1[3],
                                    m2[0],m2[1],m2[2],m2[3], m3[0],m3[1],m3[2],m3[3]};
            #pragma unroll
            for (int i = 0; i < 16; ++i) {
                // per byte: nz flag at bit7, then gather 4 flags -> nibble
                const unsigned t = (w[i] & 0x7F7F7F7Fu) + 0x7F7F7F7Fu;
                const unsigned z = ((t | w[i]) & 0x80808080u) >> 7;
                nib[i] = (z * 0x10204081u) >> 28;
            }
        } else {
            const unsigned* mp = (const unsigned*)M + (size_t)b * S_LEN * S_LEN
                                    + (size_t)(q0 + row) * S_LEN + seg;
            #pragma unroll
            for (int j = 0; j < 16; ++j) {
                const u32x4_t wv = __builtin_nontemporal_load((const u32x4_t*)(mp + j * 4));
                unsigned n = 0, t;
                t = (wv[0] & 0x7FFFFFFFu) + 0x7FFFFFFFu; n |=  ((t | wv[0]) >> 31) & 1u;
                t = (wv[1] & 0x7FFFFFFFu) + 0x7FFFFFFFu; n |= (((t | wv[1]) >> 31) & 1u) << 1;
                t = (wv[2] & 0x7FFFFFFFu) + 0x7FFFFFFFu; n |= (((t | wv[2]) >> 31) & 1u) << 2;
                t = (wv[3] & 0x7FFFFFFFu) + 0x7FFFFFFFu; n |= (((t | wv[3]) >> 31) & 1u) << 3;
                nib[j] = n;
            }
        }
        unsigned lo = 0, hi = 0;
        #pragma unroll
        for (int j = 0; j < 8; ++j) { lo |= nib[j] << (4 * j); hi |= nib[8 + j] << (4 * j); }
        *(unsigned long long*)&Bm[row * BMSTR + (seg >> 3)] =
            ((unsigned long long)hi << 32) | lo;
    }
    __syncthreads();

    // A-frag: lane l -> A[l&15][(l>>4)*8 + e]
    bf16x8_t afrag[2];
    #pragma unroll
    for (int kk = 0; kk < 2; ++kk)
        afrag[kk] = *(const bf16x8_t*)&Qlds[col * QSTR + kk * 32 + kg * 8];

    // ---- Phase 1: QK^T/8 -> exp -> mask(bit) -> Plds; rowsum in regs
    float rs[4] = {0.f, 0.f, 0.f, 0.f};
    {
        const float* Kb = K + (size_t)b * S_LEN * HDIM;
        float4 A0,B0,C0,D0, A1,B1,C1,D1;

        #define LDK(f, Ax,Bx,Cx,Dx) { \
            const float* kp = Kb + (size_t)(wave*256 + (f)*16 + col) * HDIM + kg*8; \
            Ax = *(const float4*)kp;       Bx = *(const float4*)(kp + 4); \
            Cx = *(const float4*)(kp + 32); Dx = *(const float4*)(kp + 36); }

        #define STEP(f, Ax,Bx,Cx,Dx, PF, fpf) { \
            s16x8_t t0, t1; \
            t0[0]=f2bf(Ax.x); t0[1]=f2bf(Ax.y); t0[2]=f2bf(Ax.z); t0[3]=f2bf(Ax.w); \
            t0[4]=f2bf(Bx.x); t0[5]=f2bf(Bx.y); t0[6]=f2bf(Bx.z); t0[7]=f2bf(Bx.w); \
            t1[0]=f2bf(Cx.x); t1[1]=f2bf(Cx.y); t1[2]=f2bf(Cx.z); t1[3]=f2bf(Cx.w); \
            t1[4]=f2bf(Dx.x); t1[5]=f2bf(Dx.y); t1[6]=f2bf(Dx.z); t1[7]=f2bf(Dx.w); \
            if (PF) LDK(fpf, Ax,Bx,Cx,Dx); \
            f32x4_t acc = {0.f,0.f,0.f,0.f}; \
            acc = __builtin_amdgcn_mfma_f32_16x16x32_bf16(afrag[0], __builtin_bit_cast(bf16x8_t, t0), acc, 0,0,0); \
            acc = __builtin_amdgcn_mfma_f32_16x16x32_bf16(afrag[1], __builtin_bit_cast(bf16x8_t, t1), acc, 0,0,0); \
            const int c = wave*256 + (f)*16 + col; \
            _Pragma("unroll") \
            for (int r = 0; r < 4; ++r) { \
                const int row = kg*4 + r; \
                const unsigned bm = Bm[row * BMSTR + (c >> 3)]; \
                const float p = __expf(acc[r] * 0.125f); \
                const short pb = ((bm >> (col & 7)) & 1u) ? (short)0 : f2bf(p); \
                rs[r] += bf2f(pb); \
                Plds[row * PSTR + c] = pb; \
            } }

        LDK(0, A0,B0,C0,D0);
        LDK(1, A1,B1,C1,D1);
        #pragma unroll
        for (int ff = 0; ff < 16; ff += 2) {
            STEP(ff,     A0,B0,C0,D0, (ff + 2 < 16), ff + 2);
            STEP(ff + 1, A1,B1,C1,D1, (ff + 3 < 16), ff + 3);
        }
        #undef LDK
        #undef STEP
    }
    // rowsum: reduce over 16 col-lanes, one atomic per (kg,r)
    #pragma unroll
    for (int r = 0; r < 4; ++r) {
        float s = rs[r];
        s += __shfl_xor(s, 1);
        s += __shfl_xor(s, 2);
        s += __shfl_xor(s, 4);
        s += __shfl_xor(s, 8);
        if (col == 0) atomicAdd(&rowsum[kg * 4 + r], s);
    }
    __syncthreads();
    if (tid < BQ) rinv[tid] = 1.0f / rowsum[tid];   // consumed after next barrier

    // ---- Phase 2: PV, all 8 waves, k-split: wave = (khalf<<2) | colgroup
    const int hbase = (wave & 3) * 16;
    const int kbase = (wave >> 2) * 1024;
    f32x4_t cacc = {0.f, 0.f, 0.f, 0.f};
    {
        const float* Vb = V + (size_t)b * S_LEN * HDIM + hbase + col;
        float vr0[8], vr1[8];
        #define LOADV(k0, dst) { const float* vp = Vb + (size_t)((k0) + kg*8) * HDIM; \
            dst[0]=vp[0*HDIM]; dst[1]=vp[1*HDIM]; dst[2]=vp[2*HDIM]; dst[3]=vp[3*HDIM]; \
            dst[4]=vp[4*HDIM]; dst[5]=vp[5*HDIM]; dst[6]=vp[6*HDIM]; dst[7]=vp[7*HDIM]; }
        #define PACKV(src, dst) { s16x8_t t; \
            t[0]=f2bf(src[0]); t[1]=f2bf(src[1]); t[2]=f2bf(src[2]); t[3]=f2bf(src[3]); \
            t[4]=f2bf(src[4]); t[5]=f2bf(src[5]); t[6]=f2bf(src[6]); t[7]=f2bf(src[7]); \
            dst = __builtin_bit_cast(bf16x8_t, t); }
        LOADV(kbase,      vr0);
        LOADV(kbase + 32, vr1);
        #pragma unroll
        for (int kc2 = 0; kc2 < 16; ++kc2) {
            const int ke = kbase + kc2 * 64;
            {
                const bf16x8_t pa = *(const bf16x8_t*)&Plds[col * PSTR + ke + kg * 8];
                bf16x8_t vbf; PACKV(vr0, vbf);
                if (kc2 < 15) LOADV(ke + 64, vr0);
                cacc = __builtin_amdgcn_mfma_f32_16x16x32_bf16(pa, vbf, cacc, 0, 0, 0);
            }
            {
                const bf16x8_t pa = *(const bf16x8_t*)&Plds[col * PSTR + ke + 32 + kg * 8];
                bf16x8_t vbf; PACKV(vr1, vbf);
                if (kc2 < 15) LOADV(ke + 96, vr1);
                cacc = __builtin_amdgcn_mfma_f32_16x16x32_bf16(pa, vbf, cacc, 0, 0, 0);
            }
        }
        #undef LOADV
        #undef PACKV
    }
    if (wave >= 4) {
        #pragma unroll
        for (int r = 0; r < 4; ++r)
            Pvp[wave - 4][kg * 4 + r][col] = cacc[r];
    }
    __syncthreads();

    // ---- Phase 3: ctx store (waves 0-3) + attn stream-out (all waves)
    if (wave < 4) {
        #pragma unroll
        for (int r = 0; r < 4; ++r) {
            const int row = kg * 4 + r;
            const float cv = (cacc[r] + Pvp[wave][row][col]) * rinv[row];
            __builtin_nontemporal_store(cv,
                ctx_out + ((size_t)b * S_LEN + q0 + row) * HDIM + hbase + col);
        }
    }
    {
        float* ab = attn_out + ((size_t)b * S_LEN + q0) * S_LEN;
        #pragma unroll 2
        for (int it = 0; it < 8; ++it) {
            const int flat = it * 512 + tid;     // 4096 vec8 chunks
            const int row  = flat >> 8;
            const int c0   = (flat & 255) * 8;
            const float inv = rinv[row];
            const s16x8_t pv = *(const s16x8_t*)&Plds[row * PSTR + c0];
            f32x4_t o0, o1;
            o0[0] = bf2f(pv[0]) * inv; o0[1] = bf2f(pv[1]) * inv;
            o0[2] = bf2f(pv[2]) * inv; o0[3] = bf2f(pv[3]) * inv;
            o1[0] = bf2f(pv[4]) * inv; o1[1] = bf2f(pv[5]) * inv;
            o1[2] = bf2f(pv[6]) * inv; o1[3] = bf2f(pv[7]) * inv;
            float* op = ab + (size_t)row * S_LEN + c0;
            __builtin_nontemporal_store(o0, (f32x4_t*)op);
            __builtin_nontemporal_store(o1, (f32x4_t*)(op + 4));
        }
    }
}

extern "C" void kernel_launch(void* const* d_in, const int* in_sizes, int n_in,
                              void* d_out, int out_size, void* d_ws, size_t ws_size,
                              hipStream_t stream)
{
    const float* q = (const float*)d_in[0];
    const float* k = (const float*)d_in[1];
    const float* v = (const float*)d_in[2];
    const unsigned char* mask = (const unsigned char*)d_in[3];
    int* mflags = (int*)d_ws;
    float* out = (float*)d_out;
    detect_mask<<<dim3(1), dim3(256), 0, stream>>>(mask, mflags);
    sdpa_fused<<<dim3(4096), dim3(NTHREADS), 0, stream>>>(q, k, v, mask, mflags, out);
}